// Round 11
// baseline (534.460 us; speedup 1.0000x reference)
//
#include <hip/hip_runtime.h>

// Problem constants (from reference)
#define BATCH 2048
#define T 512
#define NF 10
#define HID 30
#define S3T 1536          // 3*T sequence length after reshape/transpose
#define FEAT_PER_B 15360  // 10*1536 floats per batch element
// Workspace: BATCH * FEAT_PER_B * 4 = 125,829,120 bytes
// Layout: xpair[b][p][s][e] (p<5, s<1536, e<2) = x[b][s][2p+e] — one float2
// at (b,p,s) is the d-pair (2p,2p+1) for step s -> loads directly as v2f.

typedef float v2f __attribute__((ext_vector_type(2)));  // -> v_pk_fma_f32

#define LOG2E 1.44269504088896f

__device__ __forceinline__ float fexp(float x) {
    return __builtin_amdgcn_exp2f(x * LOG2E);   // v_mul + v_exp_f32
}
__device__ __forceinline__ float frcp(float x) {
    return __builtin_amdgcn_rcpf(x);            // v_rcp_f32
}

// Kernel 1: materialize xpair, float4 per thread (2 steps x 1 d-pair).
// R10 evidence: scalar-store version ran ~107us (~1.2 TB/s effective) --
// 4x fewer threads + 16B stores target the ~3 TB/s write-stream ceiling.
__global__ void feat_kernel(const int* __restrict__ atom_i,
                            const int* __restrict__ atom_j,
                            const float* __restrict__ dist,
                            const float* __restrict__ emb,
                            float4* __restrict__ xpair4) {
    int g = blockIdx.x * blockDim.x + threadIdx.x;
    const int total4 = BATCH * (FEAT_PER_B / 4);  // 7,864,320
    if (g >= total4) return;
    int b  = g / 3840;
    int r4 = g - b * 3840;
    int p  = r4 / 768;         // d-pair index
    int c  = r4 - p * 768;     // float4 index within the pair stream
    float vv[4];
#pragma unroll
    for (int kx = 0; kx < 4; ++kx) {
        int s = 2 * c + (kx >> 1);
        int e = kx & 1;
        int f = (2 * p + e) * S3T + s;   // flat index into featflat_b
        int t = f / 30;
        int cc = f - t * 30;
        int bt = b * T + t;
        float v;
        if (cc < 10) {
            int ai = atom_i[bt];
            v = (ai != 0) ? emb[ai * NF + cc] : 0.0f;
        } else if (cc < 20) {
            int aj = atom_j[bt];
            v = (aj != 0) ? emb[aj * NF + (cc - 10)] : 0.0f;
        } else {
            int ai = atom_i[bt];
            float dd = dist[bt];
            float ctr = (float)(cc - 19) * 0.7f;
            float df = ctr - dd;
            v = (ai != 0) ? fexp(-df * df) : 0.0f;
        }
        vv[kx] = v;
    }
    xpair4[g] = make_float4(vv[0], vv[1], vv[2], vv[3]);
}

// Kernel 2: GRU recurrence — full-dot mapping (R9/R10 winner), 2 batches per
// wave, 1024 single-wave blocks. Lane k (k<30) computes the complete gates
// for unit k of its half's batch (lanes 0-31 batch 2*blk, 32-61 2*blk+1).
//
// R11 changes (issue-trim; R10 measured ~200 VALU inst/step vs ~85 ideal):
//  - hj / x read DIRECTLY as v2f (no float4->v2f memcpy repack, no xq
//    double-buffer rotation -> kills the suspected ~30-40 movs/step)
//  - fp contract(fast) pragma: guarantee v_pk_fma_f32 fusion
//  - log2e folded into weights: r/z rows scaled by -log2e, n rows by
//    -2*log2e -> sigmoids/tanh start directly at v_exp_f32 (3 fewer muls,
//    shorter trans chain). tanh(u)=2*rcp(1+exp2(-2L*u))-1, and
//    -2L*(ai+rg*ah) = (-2L*ai) + rg*(-2L*ah), so prescaling both n-rows
//    is exact up to fp32 reassociation of a scalar factor.
//
// Wavefront fence instead of __syncthreads [R10: 576->420us]: single-wave
// block + in-order DS pipe make the barrier's vmcnt(0) drain pure loss.
// amdgpu_waves_per_eu(1,1) [R6/R9]: pressure target 512 regs so the ~120
// weight regs stay ARCH-resident (tighter ceilings AGPR-bounce them).
__attribute__((amdgpu_waves_per_eu(1, 1)))
__global__ void __launch_bounds__(64)
gru_kernel(const float* __restrict__ xpair,
           const float* __restrict__ W_ih,   // [90,10]
           const float* __restrict__ W_hh,   // [90,30]
           const float* __restrict__ b_ih,   // [90]
           const float* __restrict__ b_hh,   // [90]
           const float* __restrict__ W_out,  // [1,30]
           const float* __restrict__ b_out,  // [1]
           float* __restrict__ out) {
#pragma clang fp contract(fast)
    // Double-buffered h: [buf][half*32 + k]; slots 30,31/62,63 written by
    // the k=30,31 lanes but never read (hj covers pairs 0..14 = floats 0..29).
    __shared__ __align__(16) float hbuf[2][64];
    const int lane = threadIdx.x;
    const int half = lane >> 5;
    const int k    = lane & 31;
    const bool active = (k < HID);
    const int kk = active ? k : (HID - 1);
    const int b = blockIdx.x * 2 + half;

    const float SRZ = -LOG2E;          // r/z gates: sigmoid(x)=rcp(1+exp2(-L x))
    const float SN  = -2.0f * LOG2E;   // n gate: tanh(u)=2 rcp(1+exp2(-2L u))-1

    // Full-row hh weights: 15 v2f (j-pairs) per gate; rows 8B-aligned.
    v2f whr[15], whz[15], whn[15];
    {
        const float2* Rr = (const float2*)&W_hh[(0 * HID + kk) * HID];
        const float2* Rz = (const float2*)&W_hh[(1 * HID + kk) * HID];
        const float2* Rn = (const float2*)&W_hh[(2 * HID + kk) * HID];
#pragma unroll
        for (int j = 0; j < 15; ++j) {
            float2 tr = Rr[j], tz = Rz[j], tn = Rn[j];
            whr[j] = (v2f){tr.x * SRZ, tr.y * SRZ};
            whz[j] = (v2f){tz.x * SRZ, tz.y * SRZ};
            whn[j] = (v2f){tn.x * SN,  tn.y * SN};
        }
    }
    // Full-row ih weights: 5 v2f per gate (d-pairs match xpair layout).
    v2f wir[5], wiz[5], win[5];
    {
        const float2* Rr = (const float2*)&W_ih[(0 * HID + kk) * NF];
        const float2* Rz = (const float2*)&W_ih[(1 * HID + kk) * NF];
        const float2* Rn = (const float2*)&W_ih[(2 * HID + kk) * NF];
#pragma unroll
        for (int d = 0; d < 5; ++d) {
            float2 tr = Rr[d], tz = Rz[d], tn = Rn[d];
            wir[d] = (v2f){tr.x * SRZ, tr.y * SRZ};
            wiz[d] = (v2f){tz.x * SRZ, tz.y * SRZ};
            win[d] = (v2f){tn.x * SN,  tn.y * SN};
        }
    }
    // Biases (prescaled), folded into the first pk-fma of each dot.
    const v2f brv = (v2f){SRZ * (b_ih[0 * HID + kk] + b_hh[0 * HID + kk]), 0.0f};
    const v2f bzv = (v2f){SRZ * (b_ih[1 * HID + kk] + b_hh[1 * HID + kk]), 0.0f};
    const v2f biv = (v2f){SN * b_ih[2 * HID + kk], 0.0f};  // n biases stay split:
    const v2f bhv = (v2f){SN * b_hh[2 * HID + kk], 0.0f};  // n uses ai + rg*ah

    // 5 v2f stream pointers: xf[p][s] = d-pair (2p,2p+1) at step s.
    const float* xb = xpair + (long)b * FEAT_PER_B;
    const v2f* xf[5];
#pragma unroll
    for (int p = 0; p < 5; ++p) xf[p] = (const v2f*)(xb + p * 3072);

    hbuf[0][lane] = 0.0f;
    hbuf[1][lane] = 0.0f;
    __builtin_amdgcn_fence(__ATOMIC_ACQ_REL, "wavefront");

    float h = 0.0f;
    v2f xc[5];
#pragma unroll
    for (int p = 0; p < 5; ++p) xc[p] = xf[p][0];

#pragma unroll 2
    for (int s = 0; s < S3T; ++s) {
        const float* rb = hbuf[s & 1];
        float* wb = hbuf[(s + 1) & 1];

        // Prefetch next step's x (5 dwordx2, independent of the h chain)
        v2f xn[5];
        const int sn = (s + 1 < S3T) ? (s + 1) : s;
#pragma unroll
        for (int p = 0; p < 5; ++p) xn[p] = xf[p][sn];

        // My half's h, read directly as v2f pairs (LLVM merges to b128/b64)
        const v2f* hp = (const v2f*)&rb[half * 32];
        v2f hj[15];
#pragma unroll
        for (int j = 0; j < 15; ++j) hj[j] = hp[j];

        // 4 independent pk-fma chains; biases folded into the first fma
        v2f ar2 = whr[0] * hj[0] + brv;
        v2f az2 = whz[0] * hj[0] + bzv;
        v2f ah2 = whn[0] * hj[0] + bhv;
#pragma unroll
        for (int j = 1; j < 15; ++j) {
            ar2 += whr[j] * hj[j];
            az2 += whz[j] * hj[j];
            ah2 += whn[j] * hj[j];
        }
        v2f ai2 = win[0] * xc[0] + biv;
#pragma unroll
        for (int d = 1; d < 5; ++d) ai2 += win[d] * xc[d];
#pragma unroll
        for (int d = 0; d < 5; ++d) {
            ar2 += wir[d] * xc[d];
            az2 += wiz[d] * xc[d];
        }
        float ar = ar2.x + ar2.y;   // = -L*(dot+bias)
        float az = az2.x + az2.y;
        float ah = ah2.x + ah2.y;   // = -2L*(hh_n dot + b_hh_n)
        float ai = ai2.x + ai2.y;   // = -2L*(ih_n dot + b_ih_n)

        float rg = frcp(1.0f + __builtin_amdgcn_exp2f(ar));
        float zg = frcp(1.0f + __builtin_amdgcn_exp2f(az));
        float ng = 2.0f * frcp(1.0f + __builtin_amdgcn_exp2f(ai + rg * ah)) - 1.0f;
        h = ng + zg * (h - ng);  // (1-z)*n + z*h

        wb[half * 32 + k] = h;   // unconditional: k>=30 slots never read
        __builtin_amdgcn_fence(__ATOMIC_ACQ_REL, "wavefront");

#pragma unroll
        for (int p = 0; p < 5; ++p) xc[p] = xn[p];
    }

    // out[b] = relu(h . W_out + b_out), reduced within each 32-lane half
    float v = active ? h * W_out[kk] : 0.0f;
#pragma unroll
    for (int off = 16; off; off >>= 1) v += __shfl_xor(v, off, 32);
    if (k == 0) {
        float o = v + b_out[0];
        out[b] = o > 0.0f ? o : 0.0f;
    }
}

extern "C" void kernel_launch(void* const* d_in, const int* in_sizes, int n_in,
                              void* d_out, int out_size, void* d_ws, size_t ws_size,
                              hipStream_t stream) {
    const int* atom_i   = (const int*)d_in[0];
    const int* atom_j   = (const int*)d_in[1];
    const float* dist   = (const float*)d_in[2];
    const float* emb    = (const float*)d_in[3];
    const float* W_ih   = (const float*)d_in[4];
    const float* W_hh   = (const float*)d_in[5];
    const float* b_ih   = (const float*)d_in[6];
    const float* b_hh   = (const float*)d_in[7];
    const float* W_out  = (const float*)d_in[8];
    const float* b_out  = (const float*)d_in[9];
    float* out = (float*)d_out;
    float* xpair = (float*)d_ws;

    const int total4 = BATCH * (FEAT_PER_B / 4);
    const int threads = 256;
    const int blocks = (total4 + threads - 1) / threads;
    feat_kernel<<<blocks, threads, 0, stream>>>(atom_i, atom_j, dist, emb,
                                                (float4*)xpair);
    gru_kernel<<<BATCH / 2, 64, 0, stream>>>(xpair, W_ih, W_hh, b_ih, b_hh,
                                             W_out, b_out, out);
}

// Round 12
// 519.648 us; speedup vs baseline: 1.0285x; 1.0285x over previous
//
#include <hip/hip_runtime.h>

// Problem constants (from reference)
#define BATCH 2048
#define T 512
#define NF 10
#define HID 30
#define S3T 1536          // 3*T sequence length after reshape/transpose
#define FEAT_PER_B 15360  // 10*1536 floats per batch element
// Workspace: BATCH * FEAT_PER_B * 4 = 125,829,120 bytes
// Layout: xpair[b][p][s][e] (p<5, s<1536, e<2) = x[b][s][2p+e] — one dwordx4
// at (b,p,2*ch) = d-pair (2p,2p+1) for steps 2ch,2ch+1 -> natural v2f halves.

typedef float v2f __attribute__((ext_vector_type(2)));

#define LOG2E 1.44269504088896f

__device__ __forceinline__ float fexp(float x) {
    return __builtin_amdgcn_exp2f(x * LOG2E);   // v_exp_f32
}
__device__ __forceinline__ float frcp(float x) {
    return __builtin_amdgcn_rcpf(x);            // v_rcp_f32
}

// Force VOP3P packed fp32 FMA: d = a*b + c (2 MACs / instruction).
// R10/R11 evidence: ~200 VALU inst/step vs ~90 ideal with v2f C++ math and
// no delta from fp-contract pragmas -> LLVM is almost certainly lowering
// <2 x float> fma to 2x v_fma_f32. Non-volatile: scheduler may reorder/CSE.
__device__ __forceinline__ v2f pk_fma(v2f a, v2f b, v2f c) {
    v2f d;
    asm("v_pk_fma_f32 %0, %1, %2, %3" : "=v"(d) : "v"(a), "v"(b), "v"(c));
    return d;
}

// Kernel 1: materialize xpair, float4 per thread (2 steps x 1 d-pair).
// [R11: 107 -> ~79us vs scalar stores]
__global__ void feat_kernel(const int* __restrict__ atom_i,
                            const int* __restrict__ atom_j,
                            const float* __restrict__ dist,
                            const float* __restrict__ emb,
                            float4* __restrict__ xpair4) {
    int g = blockIdx.x * blockDim.x + threadIdx.x;
    const int total4 = BATCH * (FEAT_PER_B / 4);  // 7,864,320
    if (g >= total4) return;
    int b  = g / 3840;
    int r4 = g - b * 3840;
    int p  = r4 / 768;         // d-pair index
    int c  = r4 - p * 768;     // float4 index within the pair stream
    float vv[4];
#pragma unroll
    for (int kx = 0; kx < 4; ++kx) {
        int s = 2 * c + (kx >> 1);
        int e = kx & 1;
        int f = (2 * p + e) * S3T + s;   // flat index into featflat_b
        int t = f / 30;
        int cc = f - t * 30;
        int bt = b * T + t;
        float v;
        if (cc < 10) {
            int ai = atom_i[bt];
            v = (ai != 0) ? emb[ai * NF + cc] : 0.0f;
        } else if (cc < 20) {
            int aj = atom_j[bt];
            v = (aj != 0) ? emb[aj * NF + (cc - 10)] : 0.0f;
        } else {
            int ai = atom_i[bt];
            float dd = dist[bt];
            float ctr = (float)(cc - 19) * 0.7f;
            float df = ctr - dd;
            v = (ai != 0) ? fexp(-df * df) : 0.0f;
        }
        vv[kx] = v;
    }
    xpair4[g] = make_float4(vv[0], vv[1], vv[2], vv[3]);
}

// One GRU step: reads hbuf[PAR], writes hbuf[PAR^1]. XQ = 5 float4 chunk
// regs; IDX selects low/high v2f half (step 2ch / 2ch+1) — pure register
// aliasing, no movs (R11 lesson: narrower real loads are WORSE).
// Gates use log2e-prescaled weights: r/z rows x(-L), n rows x(-2L), so
// sigmoid(x)=rcp(1+exp2(ar)) and tanh path start directly at v_exp_f32.
// Trailing wavefront fence replaces __syncthreads [R10: 576->420us]:
// single-wave block + in-order DS pipe; the barrier's vmcnt(0) drain put
// x-prefetch HBM latency on the critical path.
#define STEP(PAR, XQ, IDX)                                                   \
    {                                                                        \
        const float4* hv = (const float4*)&hbuf[PAR][half * 32];             \
        v2f hj[16];                                                          \
        _Pragma("unroll")                                                    \
        for (int qq = 0; qq < 8; ++qq) {                                     \
            float4 tq = hv[qq];                                              \
            __builtin_memcpy(&hj[2 * qq], &tq, 16);                          \
        }                                                                    \
        v2f xc[5];                                                           \
        _Pragma("unroll")                                                    \
        for (int pp = 0; pp < 5; ++pp)                                       \
            __builtin_memcpy(&xc[pp], ((const char*)&XQ[pp]) + 8 * (IDX), 8);\
        v2f ar2 = pk_fma(whr[0], hj[0], brv);                                \
        v2f az2 = pk_fma(whz[0], hj[0], bzv);                                \
        v2f ah2 = pk_fma(whn[0], hj[0], bhv);                                \
        _Pragma("unroll")                                                    \
        for (int j = 1; j < 15; ++j) {                                       \
            ar2 = pk_fma(whr[j], hj[j], ar2);                                \
            az2 = pk_fma(whz[j], hj[j], az2);                                \
            ah2 = pk_fma(whn[j], hj[j], ah2);                                \
        }                                                                    \
        v2f ai2 = pk_fma(win[0], xc[0], biv);                                \
        _Pragma("unroll")                                                    \
        for (int d2 = 1; d2 < 5; ++d2) ai2 = pk_fma(win[d2], xc[d2], ai2);   \
        _Pragma("unroll")                                                    \
        for (int d2 = 0; d2 < 5; ++d2) {                                     \
            ar2 = pk_fma(wir[d2], xc[d2], ar2);                              \
            az2 = pk_fma(wiz[d2], xc[d2], az2);                              \
        }                                                                    \
        float ar = ar2.x + ar2.y, az = az2.x + az2.y;                        \
        float ah = ah2.x + ah2.y, ai = ai2.x + ai2.y;                        \
        float rg = frcp(1.0f + __builtin_amdgcn_exp2f(ar));                  \
        float zg = frcp(1.0f + __builtin_amdgcn_exp2f(az));                  \
        float ng =                                                           \
            2.0f * frcp(1.0f + __builtin_amdgcn_exp2f(ai + rg * ah)) - 1.0f; \
        h = ng + zg * (h - ng);                                              \
        hbuf[(PAR) ^ 1][half * 32 + k] = h;                                  \
        __builtin_amdgcn_fence(__ATOMIC_ACQ_REL, "wavefront");               \
    }

// Kernel 2: GRU recurrence — full-dot mapping (R9/R10 winner), 2 batches per
// wave, 1024 single-wave blocks. Lane k (k<30) computes the complete gates
// for unit k of its half's batch (lanes 0-31 batch 2*blk, 32-61 2*blk+1).
// amdgpu_waves_per_eu(1,1) [R6/R9]: pressure target 512 regs so the ~120
// weight regs stay ARCH-resident (tighter ceilings AGPR-bounce them).
__attribute__((amdgpu_waves_per_eu(1, 1)))
__global__ void __launch_bounds__(64)
gru_kernel(const float* __restrict__ xpair,
           const float* __restrict__ W_ih,   // [90,10]
           const float* __restrict__ W_hh,   // [90,30]
           const float* __restrict__ b_ih,   // [90]
           const float* __restrict__ b_hh,   // [90]
           const float* __restrict__ W_out,  // [1,30]
           const float* __restrict__ b_out,  // [1]
           float* __restrict__ out) {
    // Double-buffered h: [buf][half*32 + k]; slots 30,31/62,63 written by
    // k=30,31 lanes but never read (hj pair 15 is loaded but unused).
    __shared__ __align__(16) float hbuf[2][64];
    const int lane = threadIdx.x;
    const int half = lane >> 5;
    const int k    = lane & 31;
    const bool active = (k < HID);
    const int kk = active ? k : (HID - 1);
    const int b = blockIdx.x * 2 + half;

    const float SRZ = -LOG2E;          // sigmoid(x) = rcp(1+exp2(-L x))
    const float SN  = -2.0f * LOG2E;   // tanh(u) = 2 rcp(1+exp2(-2L u)) - 1

    // Full-row hh weights: 15 v2f (j-pairs) per gate, log2e-prescaled.
    v2f whr[15], whz[15], whn[15];
    {
        const float2* Rr = (const float2*)&W_hh[(0 * HID + kk) * HID];
        const float2* Rz = (const float2*)&W_hh[(1 * HID + kk) * HID];
        const float2* Rn = (const float2*)&W_hh[(2 * HID + kk) * HID];
#pragma unroll
        for (int j = 0; j < 15; ++j) {
            float2 tr = Rr[j], tz = Rz[j], tn = Rn[j];
            whr[j] = (v2f){tr.x * SRZ, tr.y * SRZ};
            whz[j] = (v2f){tz.x * SRZ, tz.y * SRZ};
            whn[j] = (v2f){tn.x * SN,  tn.y * SN};
        }
    }
    // Full-row ih weights: 5 v2f per gate (d-pairs match xpair layout).
    v2f wir[5], wiz[5], win[5];
    {
        const float2* Rr = (const float2*)&W_ih[(0 * HID + kk) * NF];
        const float2* Rz = (const float2*)&W_ih[(1 * HID + kk) * NF];
        const float2* Rn = (const float2*)&W_ih[(2 * HID + kk) * NF];
#pragma unroll
        for (int d = 0; d < 5; ++d) {
            float2 tr = Rr[d], tz = Rz[d], tn = Rn[d];
            wir[d] = (v2f){tr.x * SRZ, tr.y * SRZ};
            wiz[d] = (v2f){tz.x * SRZ, tz.y * SRZ};
            win[d] = (v2f){tn.x * SN,  tn.y * SN};
        }
    }
    // Biases (prescaled), folded into the first pk-fma of each dot.
    const v2f brv = (v2f){SRZ * (b_ih[0 * HID + kk] + b_hh[0 * HID + kk]), 0.0f};
    const v2f bzv = (v2f){SRZ * (b_ih[1 * HID + kk] + b_hh[1 * HID + kk]), 0.0f};
    const v2f biv = (v2f){SN * b_ih[2 * HID + kk], 0.0f};  // n biases stay split:
    const v2f bhv = (v2f){SN * b_hh[2 * HID + kk], 0.0f};  // n uses ai + rg*ah

    // 5 chunk base pointers: xa[p][ch] = d-pair (2p,2p+1), steps 2ch,2ch+1
    const float* xb = xpair + (long)b * FEAT_PER_B;
    const float4* xa[5];
#pragma unroll
    for (int p = 0; p < 5; ++p) xa[p] = (const float4*)(xb + p * 3072);

    hbuf[0][lane] = 0.0f;
    hbuf[1][lane] = 0.0f;
    __builtin_amdgcn_fence(__ATOMIC_ACQ_REL, "wavefront");

    float h = 0.0f;
    float4 xq0[5], xq1[5];
#pragma unroll
    for (int p = 0; p < 5; ++p) xq0[p] = xa[p][0];

    // 768 chunks of 2 steps, in pairs for compile-time buffer parity
    for (int c2 = 0; c2 < 768; c2 += 2) {
#pragma unroll
        for (int p = 0; p < 5; ++p) xq1[p] = xa[p][c2 + 1];
        STEP(0, xq0, 0);   // step 2*c2
        STEP(1, xq0, 1);   // step 2*c2+1
        const int cn = (c2 + 2 < 768) ? (c2 + 2) : 767;  // clamp final OOB
#pragma unroll
        for (int p = 0; p < 5; ++p) xq0[p] = xa[p][cn];
        STEP(0, xq1, 0);   // step 2*c2+2
        STEP(1, xq1, 1);   // step 2*c2+3
    }

    // out[b] = relu(h . W_out + b_out), reduced within each 32-lane half
    float v = active ? h * W_out[kk] : 0.0f;
#pragma unroll
    for (int off = 16; off; off >>= 1) v += __shfl_xor(v, off, 32);
    if (k == 0) {
        float o = v + b_out[0];
        out[b] = o > 0.0f ? o : 0.0f;
    }
}

extern "C" void kernel_launch(void* const* d_in, const int* in_sizes, int n_in,
                              void* d_out, int out_size, void* d_ws, size_t ws_size,
                              hipStream_t stream) {
    const int* atom_i   = (const int*)d_in[0];
    const int* atom_j   = (const int*)d_in[1];
    const float* dist   = (const float*)d_in[2];
    const float* emb    = (const float*)d_in[3];
    const float* W_ih   = (const float*)d_in[4];
    const float* W_hh   = (const float*)d_in[5];
    const float* b_ih   = (const float*)d_in[6];
    const float* b_hh   = (const float*)d_in[7];
    const float* W_out  = (const float*)d_in[8];
    const float* b_out  = (const float*)d_in[9];
    float* out = (float*)d_out;
    float* xpair = (float*)d_ws;

    const int total4 = BATCH * (FEAT_PER_B / 4);
    const int threads = 256;
    const int blocks = (total4 + threads - 1) / threads;
    feat_kernel<<<blocks, threads, 0, stream>>>(atom_i, atom_j, dist, emb,
                                                (float4*)xpair);
    gru_kernel<<<BATCH / 2, 64, 0, stream>>>(xpair, W_ih, W_hh, b_ih, b_hh,
                                             W_out, b_out, out);
}